// Round 1
// baseline (962.405 us; speedup 1.0000x reference)
//
#include <hip/hip_runtime.h>

// Fused SIREN INR: FF encode -> 6 sine GEMM layers -> 3-wide linear out.
// Strategy: weights cast to fp16 once into d_ws; one workgroup owns 128
// tokens; activations live entirely in LDS ([token][feat], stride 520 f16 =
// 1040B = 65*16B -> conflict-optimal for ds_read_b128). Each layer is a
// C[o][t] = W * h^T MFMA GEMM (weights are the A operand so A-frags are 16B
// contiguous global loads; h is the B operand so B-frags are contiguous
// ds_read_b128; C-layout emits 4 consecutive features per lane -> packed b64
// LDS writeback of sin(30*(x+b)) with no transpose).

#define L_TOTAL 262144
#define TOK 128
#define HSTR 520          // fp16 elems per token row in LDS (512 + 8 pad)
#define THREADS 512

typedef _Float16 f16x8 __attribute__((ext_vector_type(8)));
typedef _Float16 f16x4 __attribute__((ext_vector_type(4)));
typedef float    f32x4 __attribute__((ext_vector_type(4)));

__device__ __forceinline__ float sin_rev(float rev) {
  // sin(2*pi*rev) via v_fract + v_sin (v_sin takes revolutions)
  return __builtin_amdgcn_sinf(__builtin_amdgcn_fractf(rev));
}

__global__ void convert_weights(const float* __restrict__ Wf,
                                const float* __restrict__ Wh,
                                const float* __restrict__ Wo,
                                _Float16* __restrict__ o) {
  int i = blockIdx.x * blockDim.x + threadIdx.x;
  const int n1 = 512 * 256;                 // W_first
  const int n2 = n1 + 5 * 512 * 512;        // W_hidden
  const int total = n2 + 16 * 512;          // W_out padded to 16 rows
  if (i >= total) return;
  float v;
  if (i < n1) {
    v = Wf[i];
  } else if (i < n2) {
    v = Wh[i - n1];
  } else {
    int r = (i - n2) >> 9, c = (i - n2) & 511;
    v = (r < 3) ? Wo[r * 512 + c] : 0.0f;
  }
  o[i] = (_Float16)v;
}

// One sine layer: h <- sin(30*(W h + b)). M=512 outs (8 waves x 64), N=128
// tokens (8 ntiles), K templated (256 for first layer, 512 for hidden).
template <int K>
__device__ __forceinline__ void sine_layer(const _Float16* __restrict__ W,
                                           const float* __restrict__ bias,
                                           _Float16* hb, int lr, int lg,
                                           int m0) {
  f32x4 acc[4][8];
#pragma unroll
  for (int mt = 0; mt < 4; ++mt)
#pragma unroll
    for (int nt = 0; nt < 8; ++nt)
      acc[mt][nt] = (f32x4){0.f, 0.f, 0.f, 0.f};

#pragma unroll 2
  for (int ks = 0; ks < K / 32; ++ks) {
    const int k0 = ks * 32 + lg * 8;
    f16x8 a[4], b[8];
#pragma unroll
    for (int mt = 0; mt < 4; ++mt)
      a[mt] = *(const f16x8*)&W[(m0 + mt * 16 + lr) * K + k0];
#pragma unroll
    for (int nt = 0; nt < 8; ++nt)
      b[nt] = *(const f16x8*)&hb[(nt * 16 + lr) * HSTR + k0];
#pragma unroll
    for (int mt = 0; mt < 4; ++mt)
#pragma unroll
      for (int nt = 0; nt < 8; ++nt)
        acc[mt][nt] = __builtin_amdgcn_mfma_f32_16x16x32_f16(
            a[mt], b[nt], acc[mt][nt], 0, 0, 0);
  }
  __syncthreads();  // all reads of hb done before overwrite
#pragma unroll
  for (int mt = 0; mt < 4; ++mt) {
    const int ob = m0 + mt * 16 + lg * 4;  // 4 consecutive out-features
    const f32x4 bb = *(const f32x4*)&bias[ob];
#pragma unroll
    for (int nt = 0; nt < 8; ++nt) {
      f16x4 hv;
#pragma unroll
      for (int r = 0; r < 4; ++r) {
        float pre = 30.0f * (acc[mt][nt][r] + bb[r]);
        hv[r] = (_Float16)sin_rev(pre * 0.15915494309189535f);
      }
      *(f16x4*)&hb[(nt * 16 + lr) * HSTR + ob] = hv;
    }
  }
  __syncthreads();
}

__global__ __launch_bounds__(THREADS, 2) void siren_kernel(
    const float* __restrict__ coords, const float* __restrict__ bff,
    const float* __restrict__ b_first, const float* __restrict__ b_hidden,
    const float* __restrict__ b_out, const _Float16* __restrict__ wf,
    const _Float16* __restrict__ wh, const _Float16* __restrict__ wo,
    float* __restrict__ out) {
  extern __shared__ _Float16 hb[];  // [TOK][HSTR]
  const int tid = threadIdx.x;
  const int t0 = blockIdx.x * TOK;

  // ---- Fourier features: h[t][j]=sin(2pi proj_j), h[t][128+j]=cos ----
  {
    const int t = tid >> 2;              // 0..127
    const int jb = (tid & 3) << 5;       // 0,32,64,96
    const float c0 = coords[(t0 + t) * 3 + 0];
    const float c1 = coords[(t0 + t) * 3 + 1];
    const float c2 = coords[(t0 + t) * 3 + 2];
    _Float16* hr = &hb[t * HSTR];
#pragma unroll 4
    for (int j = jb; j < jb + 32; ++j) {
      // proj in revolutions = coords @ B_ff (reference multiplies by 2pi)
      float r = c0 * bff[j] + c1 * bff[128 + j] + c2 * bff[256 + j];
      float fr = __builtin_amdgcn_fractf(r);
      hr[j] = (_Float16)__builtin_amdgcn_sinf(fr);
      hr[128 + j] = (_Float16)__builtin_amdgcn_cosf(fr);
    }
  }
  __syncthreads();

  const int lane = tid & 63;
  const int lr = lane & 15;   // A: weight row / B: token / C: token col
  const int lg = lane >> 4;   // k-group for frags, row-group for C
  const int m0 = (tid >> 6) * 64;  // wave's 64-feature output slice

  sine_layer<256>(wf, b_first, hb, lr, lg, m0);
#pragma unroll 1
  for (int l = 0; l < 5; ++l)
    sine_layer<512>(wh + l * (512 * 512), b_hidden + l * 512, hb, lr, lg, m0);

  // ---- final linear: out[t][0..2], one token-tile per wave ----
  {
    const int wave = tid >> 6;
    f32x4 acc = {0.f, 0.f, 0.f, 0.f};
#pragma unroll
    for (int ks = 0; ks < 16; ++ks) {
      const int k0 = ks * 32 + lg * 8;
      f16x8 a = *(const f16x8*)&wo[lr * 512 + k0];
      f16x8 b = *(const f16x8*)&hb[(wave * 16 + lr) * HSTR + k0];
      acc = __builtin_amdgcn_mfma_f32_16x16x32_f16(a, b, acc, 0, 0, 0);
    }
    if (lg == 0) {  // rows 0..3 of C live in lanes 0..15; o = reg index
      const int t = t0 + wave * 16 + lr;
      out[t * 3 + 0] = acc[0] + b_out[0];
      out[t * 3 + 1] = acc[1] + b_out[1];
      out[t * 3 + 2] = acc[2] + b_out[2];
    }
  }
}

extern "C" void kernel_launch(void* const* d_in, const int* in_sizes, int n_in,
                              void* d_out, int out_size, void* d_ws,
                              size_t ws_size, hipStream_t stream) {
  const float* coords = (const float*)d_in[0];
  const float* bff    = (const float*)d_in[1];
  const float* Wf     = (const float*)d_in[2];
  const float* bf     = (const float*)d_in[3];
  const float* Wh     = (const float*)d_in[4];
  const float* bh     = (const float*)d_in[5];
  const float* Wo     = (const float*)d_in[6];
  const float* bo     = (const float*)d_in[7];
  float* out = (float*)d_out;

  _Float16* w16 = (_Float16*)d_ws;
  const int n1 = 512 * 256;
  const int n2 = n1 + 5 * 512 * 512;
  const int total = n2 + 16 * 512;  // ~2.9 MB fp16 in d_ws

  convert_weights<<<(total + 255) / 256, 256, 0, stream>>>(Wf, Wh, Wo, w16);

  const size_t lds_bytes = (size_t)TOK * HSTR * sizeof(_Float16);  // 133120
  siren_kernel<<<L_TOTAL / TOK, THREADS, lds_bytes, stream>>>(
      coords, bff, bf, bh, bo, w16, w16 + n1, w16 + n2, out);
}